// Round 5
// baseline (600.790 us; speedup 1.0000x reference)
//
#include <hip/hip_runtime.h>
#include <hip/hip_cooperative_groups.h>

namespace cg = cooperative_groups;

// Problem constants (from reference)
#define NN 50000      // nodes
#define NE 800000     // edges
#define NR 16         // relations == IN_DIM
#define HD 128        // hidden/out dim
#define LIND 512      // MLP hidden

// Frontier capacities (expected ~16 / ~256 nodes, ~16 / ~256 edges)
#define CAP1 1024
#define CAP0 4096
#define E0CAP 4096
#define E1CAP 32768

// counter slots
#define C_N1 0
#define C_N0 1
#define C_E0 2
#define C_E1 3

struct Params {
    const int* cls; const float* norm; const int* src; const int* dst;
    const float* W0; const float* W1; const float* W2;
    const float* a1w; const float* a1b; const float* a2w; const float* a2b;
    const float* c1w; const float* c1b; const float* c2w; const float* c2b;
    float* out;
    int* cnt; int* map1; int* map0; int* list1; int* list0;
    int* e0_src; int* e1_src; int* e1_dslot;
    float* M0; float* w0sum; float* msg1; float* agg1; float* msg2;
    float* partA; float* partC;
};

// One cooperative kernel; 9 phases separated by grid.sync().
// 512 blocks x 256 threads = 2 blocks/CU -> co-resident by construction.
__global__ void __launch_bounds__(256, 2) k_fused(Params p) {
    cg::grid_group grid = cg::this_grid();
    const int t = threadIdx.x;
    const int gtid = blockIdx.x * 256 + t;
    const int gstride = gridDim.x * 256;

    __shared__ float sh[HD];
    __shared__ float sh2[HD];
    __shared__ float shw[NR];

    // ---- P0: init (cnt+map1+map0 are contiguous ints in ws) ----
    for (int j = gtid; j < 8 + 2 * NN; j += gstride) p.cnt[j] = 0;
    for (int j = gtid; j < CAP0 * NR; j += gstride) p.w0sum[j] = 0.f;
    for (int j = gtid; j < CAP1 * HD; j += gstride) p.agg1[j] = 0.f;
    for (int j = gtid; j < NR * HD; j += gstride) {
        int c = j >> 7, o = j & 127;
        p.M0[j] = p.W0[c * ((NR + 1) * HD) + o];   // W0[c][c][o]
    }
    for (int j = gtid; j < HD + 1; j += gstride) p.out[j] = 0.f;
    grid.sync();

    // ---- P1: scanA — edges with dst==0 -> e0 list + S1 set ----
    for (int e = gtid; e < NE; e += gstride) {
        if (p.dst[e] == 0) {
            int s = p.src[e];
            int i = atomicAdd(&p.cnt[C_E0], 1);
            if (i < E0CAP) p.e0_src[i] = s;
            if (atomicCAS(&p.map1[s], 0, -1) == 0) {
                int slot = atomicAdd(&p.cnt[C_N1], 1);
                if (slot < CAP1) { p.list1[slot] = s; p.map1[s] = slot + 2; }
                else p.map1[s] = 1;
            }
        }
    }
    grid.sync();

    // ---- P2: scanB1 — edges with dst in S1 -> E1 list + S0 set ----
    for (int e = gtid; e < NE; e += gstride) {
        int m = p.map1[p.dst[e]];
        if (m >= 2) {
            int s = p.src[e];
            int i = atomicAdd(&p.cnt[C_E1], 1);
            if (i < E1CAP) { p.e1_src[i] = s; p.e1_dslot[i] = m - 2; }
            if (atomicCAS(&p.map0[s], 0, -1) == 0) {
                int slot = atomicAdd(&p.cnt[C_N0], 1);
                if (slot < CAP0) { p.list0[slot] = s; p.map0[s] = slot + 2; }
                else p.map0[s] = 1;
            }
        }
    }
    grid.sync();

    // ---- P3: scanB2 — rank-1 layer-0 aggregation: one scalar atomic per edge ----
    for (int e = gtid; e < NE; e += gstride) {
        int m = p.map0[p.dst[e]];
        if (m >= 2) {
            int s = p.src[e];
            atomicAdd(&p.w0sum[((m - 2) << 4) + p.cls[s]], p.norm[s]);
        }
    }
    grid.sync();

    // ---- P4: msg1 — expand agg0 from w0sum, relu, matvec W1[cls], * norm ----
    {
        int n0 = p.cnt[C_N0]; if (n0 > CAP0) n0 = CAP0;
        for (int b = blockIdx.x; b < n0; b += gridDim.x) {
            if (t < NR) shw[t] = p.w0sum[(b << 4) + t];
            __syncthreads();
            if (t < HD) {
                float a = 0.f;
                #pragma unroll
                for (int c = 0; c < NR; c++) a = fmaf(shw[c], p.M0[(c << 7) + t], a);
                sh[t] = fmaxf(a, 0.f);
            }
            __syncthreads();
            if (t < HD) {
                int node = p.list0[b];
                int c = p.cls[node];
                float nm = p.norm[node];
                const float* w = p.W1 + c * (HD * HD) + t;
                float acc = 0.f;
                #pragma unroll 8
                for (int i = 0; i < HD; i++) acc = fmaf(sh[i], w[i << 7], acc);
                p.msg1[(b << 7) + t] = acc * nm;
            }
            __syncthreads();
        }
    }
    grid.sync();

    // ---- P5: agg1[dslot] += msg1[slot0(src)] over E1 ----
    {
        int e1n = p.cnt[C_E1]; if (e1n > E1CAP) e1n = E1CAP;
        int total = e1n << 7;
        for (int idx = gtid; idx < total; idx += gstride) {
            int ei = idx >> 7, j = idx & 127;
            int dslot = p.e1_dslot[ei];
            int sslot = p.map0[p.e1_src[ei]] - 2;
            if (sslot >= 0 && sslot < CAP0 && dslot >= 0 && dslot < CAP1)
                atomicAdd(&p.agg1[(dslot << 7) + j], p.msg1[(sslot << 7) + j]);
        }
    }
    grid.sync();

    // ---- P6: msg2 — relu(agg1) @ W2[cls] * norm ----
    {
        int n1 = p.cnt[C_N1]; if (n1 > CAP1) n1 = CAP1;
        for (int b = blockIdx.x; b < n1; b += gridDim.x) {
            if (t < HD) sh[t] = fmaxf(p.agg1[(b << 7) + t], 0.f);
            __syncthreads();
            if (t < HD) {
                int node = p.list1[b];
                int c = p.cls[node];
                float nm = p.norm[node];
                const float* w = p.W2 + c * (HD * HD) + t;
                float acc = 0.f;
                #pragma unroll 8
                for (int i = 0; i < HD; i++) acc = fmaf(sh[i], w[i << 7], acc);
                p.msg2[(b << 7) + t] = acc * nm;
            }
            __syncthreads();
        }
    }
    grid.sync();

    // ---- P7: hidden layers — blocks 0..31, root recomputed per block (L2-hot) ----
    if (blockIdx.x < 32) {
        int e0n = p.cnt[C_E0]; if (e0n > E0CAP) e0n = E0CAP;
        if (t < HD) {
            float acc = 0.f;
            for (int i = 0; i < e0n; i++) {
                int slot = p.map1[p.e0_src[i]] - 2;
                if (slot >= 0 && slot < CAP1) acc += p.msg2[(slot << 7) + t];
            }
            sh[t] = acc;
        }
        __syncthreads();
        float mx = -3.0e38f;
        for (int i = 0; i < HD; i++) mx = fmaxf(mx, sh[i]);
        float ex = (t < HD) ? expf(sh[t] - mx) : 0.f;
        __syncthreads();
        if (t < HD) sh[t] = ex;
        __syncthreads();
        float sum = 0.f;
        for (int i = 0; i < HD; i++) sum += sh[i];
        if (t < HD) sh2[t] = ex / sum;          // sh2 := root
        __syncthreads();
        int m = blockIdx.x >> 4;                 // 0 actor, 1 critic
        int g = (blockIdx.x >> 1) & 7;           // k-slice group
        int tt = ((blockIdx.x & 1) << 8) + t;    // 0..511 output col
        int i0 = g << 4;
        const float* W = m ? p.c1w : p.a1w;
        float pp = 0.f;
        #pragma unroll
        for (int i = i0; i < i0 + 16; i++) pp = fmaf(sh2[i], W[i * LIND + tt], pp);
        (m ? p.partC : p.partA)[(g << 9) + tt] = pp;
    }
    grid.sync();

    // ---- P8: outputs — blocks 0..7 probs k-slices, block 8 value ----
    if (blockIdx.x < 8) {
        int b = blockIdx.x;
        int k0 = b << 6;
        if (t < 64) {
            int k = k0 + t;
            float s = p.a1b[k];
            #pragma unroll
            for (int g = 0; g < 8; g++) s += p.partA[(g << 9) + k];
            sh[t] = fmaxf(s, 0.f);
        }
        __syncthreads();
        if (t < HD) {
            float acc = 0.f;
            #pragma unroll 8
            for (int j = 0; j < 64; j++) acc = fmaf(sh[j], p.a2w[(k0 + j) * HD + t], acc);
            if (b == 0) acc += p.a2b[t];
            atomicAdd(&p.out[t], acc);
        }
    } else if (blockIdx.x == 8) {
        __shared__ float red[256];
        float acc = 0.f;
        for (int k = t; k < LIND; k += 256) {
            float s = p.c1b[k];
            #pragma unroll
            for (int g = 0; g < 8; g++) s += p.partC[(g << 9) + k];
            acc = fmaf(fmaxf(s, 0.f), p.c2w[k], acc);
        }
        red[t] = acc;
        __syncthreads();
        if (t == 0) {
            float vv = p.c2b[0];
            for (int k = 0; k < 256; k++) vv += red[k];
            p.out[HD] = vv;
        }
    }
}

extern "C" void kernel_launch(void* const* d_in, const int* in_sizes, int n_in,
                              void* d_out, int out_size, void* d_ws, size_t ws_size,
                              hipStream_t stream) {
    char* ws = (char*)d_ws;
    Params p;
    p.cls  = (const int*)d_in[0];
    p.norm = (const float*)d_in[1];
    p.src  = (const int*)d_in[2];
    p.dst  = (const int*)d_in[3];
    p.W0   = (const float*)d_in[4];
    p.W1   = (const float*)d_in[5];
    p.W2   = (const float*)d_in[6];
    p.a1w  = (const float*)d_in[7];
    p.a1b  = (const float*)d_in[8];
    p.a2w  = (const float*)d_in[9];
    p.a2b  = (const float*)d_in[10];
    p.c1w  = (const float*)d_in[11];
    p.c1b  = (const float*)d_in[12];
    p.c2w  = (const float*)d_in[13];
    p.c2b  = (const float*)d_in[14];
    p.out  = (float*)d_out;

    // workspace layout (bytes); cnt/map1/map0 contiguous for one-shot zeroing
    p.cnt      = (int*)(ws + 0);        // 8 ints
    p.map1     = (int*)(ws + 32);       // NN ints
    p.map0     = (int*)(ws + 200032);   // NN ints
    p.list1    = (int*)(ws + 400032);
    p.list0    = (int*)(ws + 404128);
    p.e0_src   = (int*)(ws + 420512);
    p.e1_src   = (int*)(ws + 436896);
    p.e1_dslot = (int*)(ws + 567968);
    p.M0       = (float*)(ws + 699040);  // NR*HD
    p.w0sum    = (float*)(ws + 707232);  // CAP0*NR
    p.msg1     = (float*)(ws + 969376);  // CAP0*HD
    p.agg1     = (float*)(ws + 3066528); // CAP1*HD
    p.msg2     = (float*)(ws + 3590816); // CAP1*HD
    p.partA    = (float*)(ws + 4115104); // 8*512
    p.partC    = (float*)(ws + 4131488); // 8*512

    void* args[] = { (void*)&p };
    hipLaunchCooperativeKernel((const void*)k_fused, dim3(512), dim3(256),
                               args, 0, stream);
}